// Round 12
// baseline (87.593 us; speedup 1.0000x reference)
//
#include <hip/hip_runtime.h>

typedef __attribute__((ext_vector_type(8))) short short8;
typedef __attribute__((ext_vector_type(4))) float f32x4;

#define HF 256
#define WF 256

typedef const __attribute__((address_space(1))) void gbl_void;
typedef __attribute__((address_space(3))) void lds_void;

__device__ __forceinline__ ushort f2bf(float f) {
    uint u = __builtin_bit_cast(uint, f);
    u = (u + 0x7FFFu + ((u >> 16) & 1u)) >> 16;
    return (ushort)u;
}
__device__ __forceinline__ uint pack2(float a, float b) {
    return (uint)f2bf(a) | ((uint)f2bf(b) << 16);
}
__device__ __forceinline__ float prelu(float v, float al) { return v >= 0.f ? v : al * v; }

// ---------------------------------------------------------------------------
// Fused weight prep (unchanged)
// ---------------------------------------------------------------------------
__global__ __launch_bounds__(256) void k_wprep(const float* __restrict__ w1,
                                               const float* __restrict__ w2,
                                               const float* __restrict__ wup,
                                               ushort* __restrict__ wT1,
                                               ushort* __restrict__ wT2,
                                               ushort* __restrict__ wupT,
                                               uint4* __restrict__ zeroBuf) {
    int idx = blockIdx.x * 256 + threadIdx.x;
    if (blockIdx.x == 0 && threadIdx.x < 16)
        zeroBuf[threadIdx.x] = make_uint4(0u, 0u, 0u, 0u);
    if (idx < 36864) {
        int tap = idx >> 12;
        int oc  = idx & 4095;
        int src = oc * 9 + tap;
        wT1[idx] = f2bf(w1[src]);
        wT2[idx] = f2bf(w2[src]);
    }
    if (idx < 32768) {
        int out = idx >> 7;
        int c   = idx & 127;
        int k   = out >> 6;
        int o   = out & 63;
        wupT[idx] = f2bf(wup[c * 256 + o * 4 + k]);
    }
}

// ---------------------------------------------------------------------------
// ConvTranspose2d k=2 s=2 for b=2,3 via bf16 MFMA (unchanged — known good)
// ---------------------------------------------------------------------------
__global__ __launch_bounds__(512) void k_upsample_mfma(const float* __restrict__ x1,
                                                       const ushort* __restrict__ wupT,
                                                       const float* __restrict__ bup,
                                                       ushort* __restrict__ upB) {
    __shared__ __align__(16) char lds[81920];

    const int t   = threadIdx.x;
    const int l   = t & 63;
    const int l15 = l & 15;
    const int l4  = l >> 4;
    const int w   = t >> 6;
    const int pg  = w & 3;
    const int oh  = w >> 2;
    const int i   = blockIdx.x >> 1;
    const int j0  = (blockIdx.x & 1) * 64;
    const int z   = blockIdx.y;
    const int gb  = 2 + z;

    {
        const int j  = t & 63;
        const int cg = t >> 6;
        const size_t base = ((size_t)gb * 128) * 16384 + (size_t)i * 128 + j0 + j;
        float xv[16];
#pragma unroll
        for (int r = 0; r < 2; ++r)
#pragma unroll
            for (int cc = 0; cc < 8; ++cc)
                xv[r * 8 + cc] = x1[base + (size_t)(cg * 16 + r * 8 + cc) * 16384];
#pragma unroll
        for (int r = 0; r < 2; ++r) {
            short8 pk;
#pragma unroll
            for (int cc = 0; cc < 8; ++cc) pk[cc] = (short)f2bf(xv[r * 8 + cc]);
            int ad = (j * 256 + (cg * 16 + r * 8) * 2) ^ ((j & 15) << 4);
            *(short8*)(lds + ad) = pk;
        }
    }
    {
        const uint4* src = (const uint4*)wupT;
#pragma unroll
        for (int rep = 0; rep < 8; ++rep) {
            int q   = rep * 512 + t;
            int out = q >> 4, c16 = q & 15;
            int ad  = 16384 + ((out * 256 + c16 * 16) ^ ((out & 15) << 4));
            *(uint4*)(lds + ad) = src[q];
        }
    }
    float bvv[4];
#pragma unroll
    for (int ob = 0; ob < 4; ++ob) bvv[ob] = bup[ob * 16 + l15];
    __syncthreads();

    f32x4 acc[2][4];
#pragma unroll
    for (int kk = 0; kk < 2; ++kk)
#pragma unroll
        for (int ob = 0; ob < 4; ++ob) acc[kk][ob] = (f32x4){0.f, 0.f, 0.f, 0.f};

#pragma unroll
    for (int ks = 0; ks < 4; ++ks) {
        const int cb = ks * 64 + (l4 << 4);
        const int rowA = pg * 16 + l15;
        short8 xfr = *(const short8*)(lds + ((rowA * 256 + cb) ^ ((rowA & 15) << 4)));
#pragma unroll
        for (int kk = 0; kk < 2; ++kk)
#pragma unroll
            for (int ob = 0; ob < 4; ++ob) {
                int out = (oh * 2 + kk) * 64 + ob * 16 + l15;
                short8 wfr = *(const short8*)(lds + 16384 +
                              ((out * 256 + cb) ^ ((out & 15) << 4)));
                acc[kk][ob] = __builtin_amdgcn_mfma_f32_16x16x32_bf16(xfr, wfr, acc[kk][ob], 0, 0, 0);
            }
    }
    __syncthreads();

    ushort* OUT = (ushort*)lds;
#pragma unroll
    for (int kk = 0; kk < 2; ++kk) {
        const int k = oh * 2 + kk, p = k >> 1, q = k & 1;
#pragma unroll
        for (int ob = 0; ob < 4; ++ob) {
            const int o = ob * 16 + l15;
#pragma unroll
            for (int r = 0; r < 4; ++r) {
                int jl = pg * 16 + l4 * 4 + r;
                int x  = 2 * jl + q;
                OUT[(p * 128 + x) * 64 + o] = f2bf(acc[kk][ob][r] + bvv[ob]);
            }
        }
    }
    __syncthreads();

#pragma unroll
    for (int rep = 0; rep < 4; ++rep) {
        int idx = rep * 512 + t;
        int p   = idx >> 10;
        int y   = 2 * i + p;
        uint4 v = *(const uint4*)(lds + idx * 16);
        size_t g = (size_t)(z * HF + y) * 2048 + (size_t)j0 * 16 + (idx & 1023);
        ((uint4*)upB)[g] = v;
    }
}

// ---------------------------------------------------------------------------
// k_conv v9: 1024 thr / 16 waves, tile 32x16. K-SPLIT: waves 0-7 = ks0
// (cin 0..31), waves 8-15 = ks1 (cin 32..63); each wave = R8's proven
// acc[4][4] shape (2 rows x 32 x x 64 couts) -> 0.5 ds_read/MFMA at
// 4 waves/SIMD. Partials reduced through LDS overlay after compute.
// Staging = R11 (async gload_lds, pre-swizzled source). LDS 152 KB.
// ---------------------------------------------------------------------------
template<int IN_MODE, int OUT_NHWC>
__global__ __launch_bounds__(1024, 1) void k_conv(const float* __restrict__ x2,
                                                  const ushort* __restrict__ upB,
                                                  const ushort* __restrict__ inB,
                                                  const ushort* __restrict__ wT,
                                                  const float* __restrict__ bias,
                                                  const float* __restrict__ alpha,
                                                  const uint4* __restrict__ zeroBuf,
                                                  ushort* __restrict__ outB,
                                                  float* __restrict__ outF) {
    __shared__ __align__(16) char ldsAll[155648];
    ushort* inL = (ushort*)ldsAll;               // [0, 81920): input, swz on x
    ushort* wL  = (ushort*)(ldsAll + 81920);     // [81920, 155648): weights, swz on o
    float*  redL = (float*)ldsAll;               // overlay: 128 KB partial acc

    const int t   = threadIdx.x;
    const int wv  = t >> 6;
    const int wk  = wv & 7;          // row-pair id (0..7)
    const int ks  = wv >> 3;         // K-half (0,1)
    const int l   = t & 63;
    const int l15 = l & 15;
    const int l4  = l >> 4;
    const int x0  = (blockIdx.x & 7) * 32;
    const int y0  = (blockIdx.x >> 3) * 16;
    const int b   = blockIdx.y;

    // ---- stage ALL weights: linear dest, pre-swizzled source (4608 uint4)
    {
        const char* wTb = (const char*)wT;
#pragma unroll
        for (int rep = 0; rep < 4; ++rep) {
            int d   = rep * 1024 + t;
            int tap = d >> 9;
            int dp  = d & 511;
            int s   = (tap << 9) + (dp ^ ((dp >> 3) & 7));
            __builtin_amdgcn_global_load_lds(
                (gbl_void*)(wTb + (size_t)s * 16),
                (lds_void*)((char*)wL + (size_t)((rep << 10) + (wv << 6)) * 16),
                16, 0, 0);
        }
        if (wv < 8) {                              // tail: 4096..4607
            int d   = 4096 + (wv << 6) + l;
            int tap = d >> 9;
            int dp  = d & 511;
            int s   = (tap << 9) + (dp ^ ((dp >> 3) & 7));
            __builtin_amdgcn_global_load_lds(
                (gbl_void*)(wTb + (size_t)s * 16),
                (lds_void*)((char*)wL + (size_t)(4096 + (wv << 6)) * 16),
                16, 0, 0);
        }
    }

    // ---- stage input tile (18 x 34 x 64ch = 4896 uint4, padded to 5120)
    if (IN_MODE == 1 || b >= 2) {
        const ushort* src0 = (IN_MODE == 1) ? inB : upB;
        const int bb = (IN_MODE == 1) ? b : (b - 2);
#pragma unroll
        for (int rep = 0; rep < 5; ++rep) {
            int d  = rep * 1024 + t;
            int r  = d / 272;
            int wi = d - r * 272;
            int wq = wi ^ ((wi >> 3) & 7);
            int x  = wq >> 3, c8 = wq & 7;
            int gy = y0 - 1 + r;
            int gx = x0 - 1 + x;
            const void* g;
            if (d < 4896 && (unsigned)gy < HF && (unsigned)gx < WF) {
                size_t pos = (size_t)(bb * HF + gy) * WF + gx;
                g = (const void*)(src0 + pos * 64 + c8 * 8);
            } else {
                g = (const void*)zeroBuf;
            }
            __builtin_amdgcn_global_load_lds(
                (gbl_void*)g,
                (lds_void*)((char*)inL + (size_t)((rep << 10) + (wv << 6)) * 16),
                16, 0, 0);
        }
    } else {
        for (int q = t; q < 18 * 34 * 8; q += 1024) {
            int r   = q / 272;
            int rem = q - r * 272;
            int x   = rem >> 3;
            int c8  = rem & 7;
            int gy = y0 - 1 + r;
            int gx = x0 - 1 + x;
            uint4 v = make_uint4(0u, 0u, 0u, 0u);
            if ((unsigned)gy < HF && (unsigned)gx < WF) {
                size_t pos = (size_t)(b * HF + gy) * WF + gx;
                const float4* s = (const float4*)(x2 + pos * 64 + c8 * 8);
                float4 u0 = s[0], u1 = s[1];
                v = make_uint4(pack2(u0.x, u0.y), pack2(u0.z, u0.w),
                               pack2(u1.x, u1.y), pack2(u1.z, u1.w));
            }
            int ad = (q * 16) ^ ((x & 7) << 4);
            *(uint4*)((char*)inL + ad) = v;
        }
    }
    __syncthreads();

    f32x4 acc[4][4];   // [m][nf]
#pragma unroll
    for (int m = 0; m < 4; ++m)
#pragma unroll
        for (int nf = 0; nf < 4; ++nf) acc[m][nf] = (f32x4){0.f, 0.f, 0.f, 0.f};

    const int ksb = ks * 64 + (l4 << 4);   // byte offset of this wave's K-half chunk

    // ---- K-loop: 9 taps, this wave's K-half only; 8 reads / 16 MFMA
#pragma unroll 1
    for (int tap = 0; tap < 9; ++tap) {
        const int ky = tap / 3;
        const int kx = tap - ky * 3;
        const char* wPage = (const char*)wL + tap * 8192;
        short8 wfr[4];
#pragma unroll
        for (int nf = 0; nf < 4; ++nf) {
            int o = nf * 16 + l15;
            int ad = (o * 128 + ksb) ^ ((o & 7) << 4);
            wfr[nf] = *(const short8*)(wPage + ad);
        }
#pragma unroll
        for (int m = 0; m < 4; ++m) {
            int ry = wk * 2 + (m >> 1) + ky;
            int xl = (m & 1) * 16 + l15 + kx;
            int ad = ((ry * 34 + xl) * 128 + ksb) ^ ((xl & 7) << 4);
            short8 ifr = *(const short8*)((const char*)inL + ad);
#pragma unroll
            for (int nf = 0; nf < 4; ++nf) {
                if (OUT_NHWC)
                    acc[m][nf] = __builtin_amdgcn_mfma_f32_16x16x32_bf16(
                        wfr[nf], ifr, acc[m][nf], 0, 0, 0);   // row=cout, col=pos
                else
                    acc[m][nf] = __builtin_amdgcn_mfma_f32_16x16x32_bf16(
                        ifr, wfr[nf], acc[m][nf], 0, 0, 0);   // row=pos, col=cout
            }
        }
    }

    // ---- reduce K-halves through LDS overlay (input/weights now dead)
    __syncthreads();
    if (ks == 1) {
#pragma unroll
        for (int m = 0; m < 4; ++m)
#pragma unroll
            for (int nf = 0; nf < 4; ++nf)
                *(f32x4*)(redL + (size_t)(((wk * 16 + m * 4 + nf) * 64 + l) * 4)) = acc[m][nf];
    }
    __syncthreads();
    if (ks == 0) {
        const float al = alpha[0];
#pragma unroll
        for (int m = 0; m < 4; ++m)
#pragma unroll
            for (int nf = 0; nf < 4; ++nf) {
                f32x4 p = *(const f32x4*)(redL + (size_t)(((wk * 16 + m * 4 + nf) * 64 + l) * 4));
                acc[m][nf].x += p.x; acc[m][nf].y += p.y;
                acc[m][nf].z += p.z; acc[m][nf].w += p.w;
            }
        if (OUT_NHWC) {
            float4 bv[4];
#pragma unroll
            for (int nf = 0; nf < 4; ++nf) bv[nf] = *(const float4*)(bias + nf * 16 + (l4 << 2));
#pragma unroll
            for (int m = 0; m < 4; ++m) {
                int y = y0 + wk * 2 + (m >> 1);
                int x = x0 + (m & 1) * 16 + l15;
#pragma unroll
                for (int nf = 0; nf < 4; ++nf) {
                    f32x4 v = acc[m][nf];
                    uint lo = pack2(prelu(v.x + bv[nf].x, al), prelu(v.y + bv[nf].y, al));
                    uint hi = pack2(prelu(v.z + bv[nf].z, al), prelu(v.w + bv[nf].w, al));
                    int cb = nf * 16 + (l4 << 2);
                    *(uint2*)(outB + ((size_t)(b * HF + y) * WF + x) * 64 + cb) =
                        make_uint2(lo, hi);
                }
            }
        } else {
            float bb[4];
#pragma unroll
            for (int nf = 0; nf < 4; ++nf) bb[nf] = bias[nf * 16 + l15];
#pragma unroll
            for (int m = 0; m < 4; ++m) {
                int y  = y0 + wk * 2 + (m >> 1);
                int xb = x0 + (m & 1) * 16 + (l4 << 2);
#pragma unroll
                for (int nf = 0; nf < 4; ++nf) {
                    f32x4 v = acc[m][nf];
                    int cout = nf * 16 + l15;
                    float4 st;
                    st.x = prelu(v.x + bb[nf], al);
                    st.y = prelu(v.y + bb[nf], al);
                    st.z = prelu(v.z + bb[nf], al);
                    st.w = prelu(v.w + bb[nf], al);
                    *(float4*)(outF + (((size_t)b * 64 + cout) << 16) + y * WF + xb) = st;
                }
            }
        }
    }
}

// ---------------------------------------------------------------------------
extern "C" void kernel_launch(void* const* d_in, const int* in_sizes, int n_in,
                              void* d_out, int out_size, void* d_ws, size_t ws_size,
                              hipStream_t stream) {
    const float* x1  = (const float*)d_in[0];
    const float* x2  = (const float*)d_in[1];
    const float* wup = (const float*)d_in[2];
    const float* bup = (const float*)d_in[3];
    const float* w1  = (const float*)d_in[4];
    const float* b1  = (const float*)d_in[5];
    const float* a1  = (const float*)d_in[6];
    const float* w2  = (const float*)d_in[7];
    const float* b2  = (const float*)d_in[8];
    const float* a2  = (const float*)d_in[9];

    char* ws = (char*)d_ws;
    ushort* upB  = (ushort*)ws;                          // 16 MiB (b=2,3 NHWC bf16)
    ushort* hB   = (ushort*)(ws + (size_t)(16 << 20));   // 32 MiB (NHWC bf16)
    ushort* wT1  = (ushort*)(ws + (size_t)(48 << 20));   // 72 KiB
    ushort* wT2  = wT1 + 9 * 64 * 64;                    // 72 KiB
    ushort* wupT = wT2 + 9 * 64 * 64;                    // 64 KiB
    uint4*  zeroBuf = (uint4*)(ws + (size_t)(49 << 20)); // 256 B, zeroed by k_wprep
    float* out = (float*)d_out;

    k_wprep<<<144, 256, 0, stream>>>(w1, w2, wup, wT1, wT2, wupT, zeroBuf);
    k_upsample_mfma<<<dim3(256, 2), 512, 0, stream>>>(x1, wupT, bup, upB);
    k_conv<0, 1><<<dim3(128, 4), 1024, 0, stream>>>(x2, upB, nullptr, wT1, b1, a1, zeroBuf, hB, nullptr);
    k_conv<1, 0><<<dim3(128, 4), 1024, 0, stream>>>(nullptr, nullptr, hB, wT2, b2, a2, zeroBuf, nullptr, out);
}

// Round 13
// 81.877 us; speedup vs baseline: 1.0698x; 1.0698x over previous
//
#include <hip/hip_runtime.h>

typedef __attribute__((ext_vector_type(8))) short short8;
typedef __attribute__((ext_vector_type(4))) float f32x4;

#define HF 256
#define WF 256

typedef const __attribute__((address_space(1))) void gbl_void;
typedef __attribute__((address_space(3))) void lds_void;

__device__ __forceinline__ ushort f2bf(float f) {
    uint u = __builtin_bit_cast(uint, f);
    u = (u + 0x7FFFu + ((u >> 16) & 1u)) >> 16;
    return (ushort)u;
}
__device__ __forceinline__ uint pack2(float a, float b) {
    return (uint)f2bf(a) | ((uint)f2bf(b) << 16);
}
__device__ __forceinline__ float prelu(float v, float al) { return v >= 0.f ? v : al * v; }

// ---------------------------------------------------------------------------
// Fused weight prep (unchanged)
// ---------------------------------------------------------------------------
__global__ __launch_bounds__(256) void k_wprep(const float* __restrict__ w1,
                                               const float* __restrict__ w2,
                                               const float* __restrict__ wup,
                                               ushort* __restrict__ wT1,
                                               ushort* __restrict__ wT2,
                                               ushort* __restrict__ wupT,
                                               uint4* __restrict__ zeroBuf) {
    int idx = blockIdx.x * 256 + threadIdx.x;
    if (blockIdx.x == 0 && threadIdx.x < 16)
        zeroBuf[threadIdx.x] = make_uint4(0u, 0u, 0u, 0u);
    if (idx < 36864) {
        int tap = idx >> 12;
        int oc  = idx & 4095;
        int src = oc * 9 + tap;
        wT1[idx] = f2bf(w1[src]);
        wT2[idx] = f2bf(w2[src]);
    }
    if (idx < 32768) {
        int out = idx >> 7;
        int c   = idx & 127;
        int k   = out >> 6;
        int o   = out & 63;
        wupT[idx] = f2bf(wup[c * 256 + o * 4 + k]);
    }
}

// ---------------------------------------------------------------------------
// ConvTranspose2d k=2 s=2 for b=2,3 via bf16 MFMA (unchanged — known good)
// ---------------------------------------------------------------------------
__global__ __launch_bounds__(512) void k_upsample_mfma(const float* __restrict__ x1,
                                                       const ushort* __restrict__ wupT,
                                                       const float* __restrict__ bup,
                                                       ushort* __restrict__ upB) {
    __shared__ __align__(16) char lds[81920];

    const int t   = threadIdx.x;
    const int l   = t & 63;
    const int l15 = l & 15;
    const int l4  = l >> 4;
    const int w   = t >> 6;
    const int pg  = w & 3;
    const int oh  = w >> 2;
    const int i   = blockIdx.x >> 1;
    const int j0  = (blockIdx.x & 1) * 64;
    const int z   = blockIdx.y;
    const int gb  = 2 + z;

    {
        const int j  = t & 63;
        const int cg = t >> 6;
        const size_t base = ((size_t)gb * 128) * 16384 + (size_t)i * 128 + j0 + j;
        float xv[16];
#pragma unroll
        for (int r = 0; r < 2; ++r)
#pragma unroll
            for (int cc = 0; cc < 8; ++cc)
                xv[r * 8 + cc] = x1[base + (size_t)(cg * 16 + r * 8 + cc) * 16384];
#pragma unroll
        for (int r = 0; r < 2; ++r) {
            short8 pk;
#pragma unroll
            for (int cc = 0; cc < 8; ++cc) pk[cc] = (short)f2bf(xv[r * 8 + cc]);
            int ad = (j * 256 + (cg * 16 + r * 8) * 2) ^ ((j & 15) << 4);
            *(short8*)(lds + ad) = pk;
        }
    }
    {
        const uint4* src = (const uint4*)wupT;
#pragma unroll
        for (int rep = 0; rep < 8; ++rep) {
            int q   = rep * 512 + t;
            int out = q >> 4, c16 = q & 15;
            int ad  = 16384 + ((out * 256 + c16 * 16) ^ ((out & 15) << 4));
            *(uint4*)(lds + ad) = src[q];
        }
    }
    float bvv[4];
#pragma unroll
    for (int ob = 0; ob < 4; ++ob) bvv[ob] = bup[ob * 16 + l15];
    __syncthreads();

    f32x4 acc[2][4];
#pragma unroll
    for (int kk = 0; kk < 2; ++kk)
#pragma unroll
        for (int ob = 0; ob < 4; ++ob) acc[kk][ob] = (f32x4){0.f, 0.f, 0.f, 0.f};

#pragma unroll
    for (int ks = 0; ks < 4; ++ks) {
        const int cb = ks * 64 + (l4 << 4);
        const int rowA = pg * 16 + l15;
        short8 xfr = *(const short8*)(lds + ((rowA * 256 + cb) ^ ((rowA & 15) << 4)));
#pragma unroll
        for (int kk = 0; kk < 2; ++kk)
#pragma unroll
            for (int ob = 0; ob < 4; ++ob) {
                int out = (oh * 2 + kk) * 64 + ob * 16 + l15;
                short8 wfr = *(const short8*)(lds + 16384 +
                              ((out * 256 + cb) ^ ((out & 15) << 4)));
                acc[kk][ob] = __builtin_amdgcn_mfma_f32_16x16x32_bf16(xfr, wfr, acc[kk][ob], 0, 0, 0);
            }
    }
    __syncthreads();

    ushort* OUT = (ushort*)lds;
#pragma unroll
    for (int kk = 0; kk < 2; ++kk) {
        const int k = oh * 2 + kk, p = k >> 1, q = k & 1;
#pragma unroll
        for (int ob = 0; ob < 4; ++ob) {
            const int o = ob * 16 + l15;
#pragma unroll
            for (int r = 0; r < 4; ++r) {
                int jl = pg * 16 + l4 * 4 + r;
                int x  = 2 * jl + q;
                OUT[(p * 128 + x) * 64 + o] = f2bf(acc[kk][ob][r] + bvv[ob]);
            }
        }
    }
    __syncthreads();

#pragma unroll
    for (int rep = 0; rep < 4; ++rep) {
        int idx = rep * 512 + t;
        int p   = idx >> 10;
        int y   = 2 * i + p;
        uint4 v = *(const uint4*)(lds + idx * 16);
        size_t g = (size_t)(z * HF + y) * 2048 + (size_t)j0 * 16 + (idx & 1023);
        ((uint4*)upB)[g] = v;
    }
}

// ---------------------------------------------------------------------------
// k_conv v10: R11 structure (1024 thr / 16 waves, tile 32x16, all weights +
// input in LDS, 1 barrier) + WAVE DE-PHASING: each wave iterates the 9 taps
// starting at (wv % 9) so DS reads and MFMA bursts of different waves
// interleave instead of phase-locking; s_setprio(1) around MFMA clusters.
// ---------------------------------------------------------------------------
template<int IN_MODE, int OUT_NHWC>
__global__ __launch_bounds__(1024, 1) void k_conv(const float* __restrict__ x2,
                                                  const ushort* __restrict__ upB,
                                                  const ushort* __restrict__ inB,
                                                  const ushort* __restrict__ wT,
                                                  const float* __restrict__ bias,
                                                  const float* __restrict__ alpha,
                                                  const uint4* __restrict__ zeroBuf,
                                                  ushort* __restrict__ outB,
                                                  float* __restrict__ outF) {
    __shared__ __align__(16) ushort inL[5120 * 8];       // 80 KB (4896 used + pad)
    __shared__ __align__(16) ushort wL[9 * 64 * 64];     // 72 KB [tap][o][c], swz on o

    const int t   = threadIdx.x;
    const int wv  = t >> 6;          // wave id -> output row (0..15)
    const int l   = t & 63;
    const int l15 = l & 15;
    const int l4  = l >> 4;
    const int x0  = (blockIdx.x & 7) * 32;
    const int y0  = (blockIdx.x >> 3) * 16;
    const int b   = blockIdx.y;

    // ---- stage ALL weights: linear dest, pre-swizzled source (4608 uint4)
    {
        const char* wTb = (const char*)wT;
#pragma unroll
        for (int rep = 0; rep < 4; ++rep) {
            int d   = rep * 1024 + t;
            int tap = d >> 9;
            int dp  = d & 511;
            int s   = (tap << 9) + (dp ^ ((dp >> 3) & 7));
            __builtin_amdgcn_global_load_lds(
                (gbl_void*)(wTb + (size_t)s * 16),
                (lds_void*)((char*)wL + (size_t)((rep << 10) + (wv << 6)) * 16),
                16, 0, 0);
        }
        if (wv < 8) {                              // wave-uniform tail: 4096..4607
            int d   = 4096 + (wv << 6) + l;
            int tap = d >> 9;
            int dp  = d & 511;
            int s   = (tap << 9) + (dp ^ ((dp >> 3) & 7));
            __builtin_amdgcn_global_load_lds(
                (gbl_void*)(wTb + (size_t)s * 16),
                (lds_void*)((char*)wL + (size_t)(4096 + (wv << 6)) * 16),
                16, 0, 0);
        }
    }

    // ---- stage input tile (18 x 34 x 64ch = 4896 uint4, padded to 5120)
    if (IN_MODE == 1 || b >= 2) {
        const ushort* src0 = (IN_MODE == 1) ? inB : upB;
        const int bb = (IN_MODE == 1) ? b : (b - 2);
#pragma unroll
        for (int rep = 0; rep < 5; ++rep) {
            int d  = rep * 1024 + t;                 // 0..5119
            int r  = d / 272;
            int wi = d - r * 272;
            int wq = wi ^ ((wi >> 3) & 7);           // pre-swizzled source element
            int x  = wq >> 3, c8 = wq & 7;
            int gy = y0 - 1 + r;
            int gx = x0 - 1 + x;
            const void* g;
            if (d < 4896 && (unsigned)gy < HF && (unsigned)gx < WF) {
                size_t pos = (size_t)(bb * HF + gy) * WF + gx;
                g = (const void*)(src0 + pos * 64 + c8 * 8);
            } else {
                g = (const void*)zeroBuf;
            }
            __builtin_amdgcn_global_load_lds(
                (gbl_void*)g,
                (lds_void*)((char*)inL + (size_t)((rep << 10) + (wv << 6)) * 16),
                16, 0, 0);
        }
    } else {
        // manual path: x2 f32 NHWC -> bf16, swizzled ds_write
        for (int q = t; q < 18 * 34 * 8; q += 1024) {
            int r   = q / 272;
            int rem = q - r * 272;
            int x   = rem >> 3;
            int c8  = rem & 7;
            int gy = y0 - 1 + r;
            int gx = x0 - 1 + x;
            uint4 v = make_uint4(0u, 0u, 0u, 0u);
            if ((unsigned)gy < HF && (unsigned)gx < WF) {
                size_t pos = (size_t)(b * HF + gy) * WF + gx;
                const float4* s = (const float4*)(x2 + pos * 64 + c8 * 8);
                float4 u0 = s[0], u1 = s[1];
                v = make_uint4(pack2(u0.x, u0.y), pack2(u0.z, u0.w),
                               pack2(u1.x, u1.y), pack2(u1.z, u1.w));
            }
            int ad = (q * 16) ^ ((x & 7) << 4);
            *(uint4*)((char*)inL + ad) = v;
        }
    }
    __syncthreads();

    f32x4 acc[2][4];   // [m][nf]
#pragma unroll
    for (int m = 0; m < 2; ++m)
#pragma unroll
        for (int nf = 0; nf < 4; ++nf) acc[m][nf] = (f32x4){0.f, 0.f, 0.f, 0.f};

    // ---- K-loop: 9 taps, pure LDS + MFMA, zero barriers.
    // Wave-staggered start tap (sum order irrelevant) de-phases DS bursts.
    int tp = wv % 9;                 // wave-uniform -> SALU
#pragma unroll 1
    for (int it = 0; it < 9; ++it) {
        const int ky = (tp * 11) >> 5;          // tp/3 for tp in [0,9)
        const int kx = tp - ky * 3;
        const char* wPage = (const char*)wL + tp * 8192;
#pragma unroll
        for (int ks = 0; ks < 2; ++ks) {
            short8 wfr[4];
#pragma unroll
            for (int nf = 0; nf < 4; ++nf) {
                int o = nf * 16 + l15;
                int ad = (o * 128 + ks * 64 + (l4 << 4)) ^ ((o & 7) << 4);
                wfr[nf] = *(const short8*)(wPage + ad);
            }
            __builtin_amdgcn_s_setprio(1);
#pragma unroll
            for (int m = 0; m < 2; ++m) {
                int ry = wv + ky;
                int xl = m * 16 + l15 + kx;
                int ad = ((ry * 34 + xl) * 128 + ks * 64 + (l4 << 4)) ^ ((xl & 7) << 4);
                short8 ifr = *(const short8*)((const char*)inL + ad);
#pragma unroll
                for (int nf = 0; nf < 4; ++nf) {
                    if (OUT_NHWC)
                        acc[m][nf] = __builtin_amdgcn_mfma_f32_16x16x32_bf16(
                            wfr[nf], ifr, acc[m][nf], 0, 0, 0);   // row=cout, col=pos
                    else
                        acc[m][nf] = __builtin_amdgcn_mfma_f32_16x16x32_bf16(
                            ifr, wfr[nf], acc[m][nf], 0, 0, 0);   // row=pos, col=cout
                }
            }
            __builtin_amdgcn_s_setprio(0);
        }
        tp = (tp == 8) ? 0 : tp + 1;
    }

    const float al = alpha[0];
    const int y = y0 + wv;
    if (OUT_NHWC) {
        float4 bv[4];
#pragma unroll
        for (int nf = 0; nf < 4; ++nf) bv[nf] = *(const float4*)(bias + nf * 16 + (l4 << 2));
#pragma unroll
        for (int m = 0; m < 2; ++m) {
            int x = x0 + m * 16 + l15;
#pragma unroll
            for (int nf = 0; nf < 4; ++nf) {
                f32x4 v = acc[m][nf];
                uint lo = pack2(prelu(v.x + bv[nf].x, al), prelu(v.y + bv[nf].y, al));
                uint hi = pack2(prelu(v.z + bv[nf].z, al), prelu(v.w + bv[nf].w, al));
                int cb = nf * 16 + (l4 << 2);
                *(uint2*)(outB + ((size_t)(b * HF + y) * WF + x) * 64 + cb) = make_uint2(lo, hi);
            }
        }
    } else {
        float bb[4];
#pragma unroll
        for (int nf = 0; nf < 4; ++nf) bb[nf] = bias[nf * 16 + l15];
#pragma unroll
        for (int m = 0; m < 2; ++m) {
            int xb = x0 + m * 16 + (l4 << 2);
#pragma unroll
            for (int nf = 0; nf < 4; ++nf) {
                f32x4 v = acc[m][nf];
                int cout = nf * 16 + l15;
                float4 st;
                st.x = prelu(v.x + bb[nf], al);
                st.y = prelu(v.y + bb[nf], al);
                st.z = prelu(v.z + bb[nf], al);
                st.w = prelu(v.w + bb[nf], al);
                *(float4*)(outF + (((size_t)b * 64 + cout) << 16) + y * WF + xb) = st;
            }
        }
    }
}

// ---------------------------------------------------------------------------
extern "C" void kernel_launch(void* const* d_in, const int* in_sizes, int n_in,
                              void* d_out, int out_size, void* d_ws, size_t ws_size,
                              hipStream_t stream) {
    const float* x1  = (const float*)d_in[0];
    const float* x2  = (const float*)d_in[1];
    const float* wup = (const float*)d_in[2];
    const float* bup = (const float*)d_in[3];
    const float* w1  = (const float*)d_in[4];
    const float* b1  = (const float*)d_in[5];
    const float* a1  = (const float*)d_in[6];
    const float* w2  = (const float*)d_in[7];
    const float* b2  = (const float*)d_in[8];
    const float* a2  = (const float*)d_in[9];

    char* ws = (char*)d_ws;
    ushort* upB  = (ushort*)ws;                          // 16 MiB (b=2,3 NHWC bf16)
    ushort* hB   = (ushort*)(ws + (size_t)(16 << 20));   // 32 MiB (NHWC bf16)
    ushort* wT1  = (ushort*)(ws + (size_t)(48 << 20));   // 72 KiB
    ushort* wT2  = wT1 + 9 * 64 * 64;                    // 72 KiB
    ushort* wupT = wT2 + 9 * 64 * 64;                    // 64 KiB
    uint4*  zeroBuf = (uint4*)(ws + (size_t)(49 << 20)); // 256 B, zeroed by k_wprep
    float* out = (float*)d_out;

    k_wprep<<<144, 256, 0, stream>>>(w1, w2, wup, wT1, wT2, wupT, zeroBuf);
    k_upsample_mfma<<<dim3(256, 2), 512, 0, stream>>>(x1, wupT, bup, upB);
    k_conv<0, 1><<<dim3(128, 4), 1024, 0, stream>>>(x2, upB, nullptr, wT1, b1, a1, zeroBuf, hB, nullptr);
    k_conv<1, 0><<<dim3(128, 4), 1024, 0, stream>>>(nullptr, nullptr, hB, wT2, b2, a2, zeroBuf, nullptr, out);
}

// Round 14
// 80.785 us; speedup vs baseline: 1.0843x; 1.0135x over previous
//
#include <hip/hip_runtime.h>

typedef __attribute__((ext_vector_type(8))) short short8;
typedef __attribute__((ext_vector_type(4))) float f32x4;

#define HF 256
#define WF 256

typedef const __attribute__((address_space(1))) void gbl_void;
typedef __attribute__((address_space(3))) void lds_void;

__device__ __forceinline__ ushort f2bf(float f) {
    uint u = __builtin_bit_cast(uint, f);
    u = (u + 0x7FFFu + ((u >> 16) & 1u)) >> 16;
    return (ushort)u;
}
__device__ __forceinline__ uint pack2(float a, float b) {
    return (uint)f2bf(a) | ((uint)f2bf(b) << 16);
}
__device__ __forceinline__ float prelu(float v, float al) { return v >= 0.f ? v : al * v; }

// ---------------------------------------------------------------------------
// Fused weight prep (unchanged)
// ---------------------------------------------------------------------------
__global__ __launch_bounds__(256) void k_wprep(const float* __restrict__ w1,
                                               const float* __restrict__ w2,
                                               const float* __restrict__ wup,
                                               ushort* __restrict__ wT1,
                                               ushort* __restrict__ wT2,
                                               ushort* __restrict__ wupT,
                                               uint4* __restrict__ zeroBuf) {
    int idx = blockIdx.x * 256 + threadIdx.x;
    if (blockIdx.x == 0 && threadIdx.x < 16)
        zeroBuf[threadIdx.x] = make_uint4(0u, 0u, 0u, 0u);
    if (idx < 36864) {
        int tap = idx >> 12;
        int oc  = idx & 4095;
        int src = oc * 9 + tap;
        wT1[idx] = f2bf(w1[src]);
        wT2[idx] = f2bf(w2[src]);
    }
    if (idx < 32768) {
        int out = idx >> 7;
        int c   = idx & 127;
        int k   = out >> 6;
        int o   = out & 63;
        wupT[idx] = f2bf(wup[c * 256 + o * 4 + k]);
    }
}

// ---------------------------------------------------------------------------
// ConvTranspose2d k=2 s=2 for b=2,3 via bf16 MFMA (unchanged — known good)
// ---------------------------------------------------------------------------
__global__ __launch_bounds__(512) void k_upsample_mfma(const float* __restrict__ x1,
                                                       const ushort* __restrict__ wupT,
                                                       const float* __restrict__ bup,
                                                       ushort* __restrict__ upB) {
    __shared__ __align__(16) char lds[81920];

    const int t   = threadIdx.x;
    const int l   = t & 63;
    const int l15 = l & 15;
    const int l4  = l >> 4;
    const int w   = t >> 6;
    const int pg  = w & 3;
    const int oh  = w >> 2;
    const int i   = blockIdx.x >> 1;
    const int j0  = (blockIdx.x & 1) * 64;
    const int z   = blockIdx.y;
    const int gb  = 2 + z;

    {
        const int j  = t & 63;
        const int cg = t >> 6;
        const size_t base = ((size_t)gb * 128) * 16384 + (size_t)i * 128 + j0 + j;
        float xv[16];
#pragma unroll
        for (int r = 0; r < 2; ++r)
#pragma unroll
            for (int cc = 0; cc < 8; ++cc)
                xv[r * 8 + cc] = x1[base + (size_t)(cg * 16 + r * 8 + cc) * 16384];
#pragma unroll
        for (int r = 0; r < 2; ++r) {
            short8 pk;
#pragma unroll
            for (int cc = 0; cc < 8; ++cc) pk[cc] = (short)f2bf(xv[r * 8 + cc]);
            int ad = (j * 256 + (cg * 16 + r * 8) * 2) ^ ((j & 15) << 4);
            *(short8*)(lds + ad) = pk;
        }
    }
    {
        const uint4* src = (const uint4*)wupT;
#pragma unroll
        for (int rep = 0; rep < 8; ++rep) {
            int q   = rep * 512 + t;
            int out = q >> 4, c16 = q & 15;
            int ad  = 16384 + ((out * 256 + c16 * 16) ^ ((out & 15) << 4));
            *(uint4*)(lds + ad) = src[q];
        }
    }
    float bvv[4];
#pragma unroll
    for (int ob = 0; ob < 4; ++ob) bvv[ob] = bup[ob * 16 + l15];
    __syncthreads();

    f32x4 acc[2][4];
#pragma unroll
    for (int kk = 0; kk < 2; ++kk)
#pragma unroll
        for (int ob = 0; ob < 4; ++ob) acc[kk][ob] = (f32x4){0.f, 0.f, 0.f, 0.f};

#pragma unroll
    for (int ks = 0; ks < 4; ++ks) {
        const int cb = ks * 64 + (l4 << 4);
        const int rowA = pg * 16 + l15;
        short8 xfr = *(const short8*)(lds + ((rowA * 256 + cb) ^ ((rowA & 15) << 4)));
#pragma unroll
        for (int kk = 0; kk < 2; ++kk)
#pragma unroll
            for (int ob = 0; ob < 4; ++ob) {
                int out = (oh * 2 + kk) * 64 + ob * 16 + l15;
                short8 wfr = *(const short8*)(lds + 16384 +
                              ((out * 256 + cb) ^ ((out & 15) << 4)));
                acc[kk][ob] = __builtin_amdgcn_mfma_f32_16x16x32_bf16(xfr, wfr, acc[kk][ob], 0, 0, 0);
            }
    }
    __syncthreads();

    ushort* OUT = (ushort*)lds;
#pragma unroll
    for (int kk = 0; kk < 2; ++kk) {
        const int k = oh * 2 + kk, p = k >> 1, q = k & 1;
#pragma unroll
        for (int ob = 0; ob < 4; ++ob) {
            const int o = ob * 16 + l15;
#pragma unroll
            for (int r = 0; r < 4; ++r) {
                int jl = pg * 16 + l4 * 4 + r;
                int x  = 2 * jl + q;
                OUT[(p * 128 + x) * 64 + o] = f2bf(acc[kk][ob][r] + bvv[ob]);
            }
        }
    }
    __syncthreads();

#pragma unroll
    for (int rep = 0; rep < 4; ++rep) {
        int idx = rep * 512 + t;
        int p   = idx >> 10;
        int y   = 2 * i + p;
        uint4 v = *(const uint4*)(lds + idx * 16);
        size_t g = (size_t)(z * HF + y) * 2048 + (size_t)j0 * 16 + (idx & 1023);
        ((uint4*)upB)[g] = v;
    }
}

// ---------------------------------------------------------------------------
// k_conv v11: R11 structure (1024 thr / 16 waves, tile 32x16, all weights +
// input in LDS, 1 barrier, async gload_lds staging) with the K-loop FULLY
// UNROLLED (compile-time taps) so the compiler can software-pipeline ds_reads
// of tap t+1 under the MFMAs of tap t (reads can't hoist across unroll-1
// boundaries — suspected source of the 2.5x latency overhead in R8-R13).
// ---------------------------------------------------------------------------
template<int IN_MODE, int OUT_NHWC>
__global__ __launch_bounds__(1024, 1) void k_conv(const float* __restrict__ x2,
                                                  const ushort* __restrict__ upB,
                                                  const ushort* __restrict__ inB,
                                                  const ushort* __restrict__ wT,
                                                  const float* __restrict__ bias,
                                                  const float* __restrict__ alpha,
                                                  const uint4* __restrict__ zeroBuf,
                                                  ushort* __restrict__ outB,
                                                  float* __restrict__ outF) {
    __shared__ __align__(16) ushort inL[5120 * 8];       // 80 KB (4896 used + pad)
    __shared__ __align__(16) ushort wL[9 * 64 * 64];     // 72 KB [tap][o][c], swz on o

    const int t   = threadIdx.x;
    const int wv  = t >> 6;          // wave id -> output row (0..15)
    const int l   = t & 63;
    const int l15 = l & 15;
    const int l4  = l >> 4;
    const int x0  = (blockIdx.x & 7) * 32;
    const int y0  = (blockIdx.x >> 3) * 16;
    const int b   = blockIdx.y;

    // ---- stage ALL weights: linear dest, pre-swizzled source (4608 uint4)
    {
        const char* wTb = (const char*)wT;
#pragma unroll
        for (int rep = 0; rep < 4; ++rep) {
            int d   = rep * 1024 + t;
            int tap = d >> 9;
            int dp  = d & 511;
            int s   = (tap << 9) + (dp ^ ((dp >> 3) & 7));
            __builtin_amdgcn_global_load_lds(
                (gbl_void*)(wTb + (size_t)s * 16),
                (lds_void*)((char*)wL + (size_t)((rep << 10) + (wv << 6)) * 16),
                16, 0, 0);
        }
        if (wv < 8) {                              // wave-uniform tail: 4096..4607
            int d   = 4096 + (wv << 6) + l;
            int tap = d >> 9;
            int dp  = d & 511;
            int s   = (tap << 9) + (dp ^ ((dp >> 3) & 7));
            __builtin_amdgcn_global_load_lds(
                (gbl_void*)(wTb + (size_t)s * 16),
                (lds_void*)((char*)wL + (size_t)(4096 + (wv << 6)) * 16),
                16, 0, 0);
        }
    }

    // ---- stage input tile (18 x 34 x 64ch = 4896 uint4, padded to 5120)
    if (IN_MODE == 1 || b >= 2) {
        const ushort* src0 = (IN_MODE == 1) ? inB : upB;
        const int bb = (IN_MODE == 1) ? b : (b - 2);
#pragma unroll
        for (int rep = 0; rep < 5; ++rep) {
            int d  = rep * 1024 + t;                 // 0..5119
            int r  = d / 272;
            int wi = d - r * 272;
            int wq = wi ^ ((wi >> 3) & 7);           // pre-swizzled source element
            int x  = wq >> 3, c8 = wq & 7;
            int gy = y0 - 1 + r;
            int gx = x0 - 1 + x;
            const void* g;
            if (d < 4896 && (unsigned)gy < HF && (unsigned)gx < WF) {
                size_t pos = (size_t)(bb * HF + gy) * WF + gx;
                g = (const void*)(src0 + pos * 64 + c8 * 8);
            } else {
                g = (const void*)zeroBuf;
            }
            __builtin_amdgcn_global_load_lds(
                (gbl_void*)g,
                (lds_void*)((char*)inL + (size_t)((rep << 10) + (wv << 6)) * 16),
                16, 0, 0);
        }
    } else {
        // manual path: x2 f32 NHWC -> bf16, swizzled ds_write
        for (int q = t; q < 18 * 34 * 8; q += 1024) {
            int r   = q / 272;
            int rem = q - r * 272;
            int x   = rem >> 3;
            int c8  = rem & 7;
            int gy = y0 - 1 + r;
            int gx = x0 - 1 + x;
            uint4 v = make_uint4(0u, 0u, 0u, 0u);
            if ((unsigned)gy < HF && (unsigned)gx < WF) {
                size_t pos = (size_t)(b * HF + gy) * WF + gx;
                const float4* s = (const float4*)(x2 + pos * 64 + c8 * 8);
                float4 u0 = s[0], u1 = s[1];
                v = make_uint4(pack2(u0.x, u0.y), pack2(u0.z, u0.w),
                               pack2(u1.x, u1.y), pack2(u1.z, u1.w));
            }
            int ad = (q * 16) ^ ((x & 7) << 4);
            *(uint4*)((char*)inL + ad) = v;
        }
    }
    __syncthreads();

    f32x4 acc[2][4];   // [m][nf]
#pragma unroll
    for (int m = 0; m < 2; ++m)
#pragma unroll
        for (int nf = 0; nf < 4; ++nf) acc[m][nf] = (f32x4){0.f, 0.f, 0.f, 0.f};

    // ---- K-loop: FULLY UNROLLED — 18 ks-units, 108 ds_reads + 144 MFMAs in
    // one scheduling window so reads pipeline under previous taps' MFMAs.
#pragma unroll
    for (int tap = 0; tap < 9; ++tap) {
        const int ky = tap / 3;
        const int kx = tap % 3;
        const char* wPage = (const char*)wL + tap * 8192;
#pragma unroll
        for (int ks = 0; ks < 2; ++ks) {
            short8 wfr[4];
#pragma unroll
            for (int nf = 0; nf < 4; ++nf) {
                int o = nf * 16 + l15;
                int ad = (o * 128 + ks * 64 + (l4 << 4)) ^ ((o & 7) << 4);
                wfr[nf] = *(const short8*)(wPage + ad);
            }
#pragma unroll
            for (int m = 0; m < 2; ++m) {
                int ry = wv + ky;
                int xl = m * 16 + l15 + kx;
                int ad = ((ry * 34 + xl) * 128 + ks * 64 + (l4 << 4)) ^ ((xl & 7) << 4);
                short8 ifr = *(const short8*)((const char*)inL + ad);
#pragma unroll
                for (int nf = 0; nf < 4; ++nf) {
                    if (OUT_NHWC)
                        acc[m][nf] = __builtin_amdgcn_mfma_f32_16x16x32_bf16(
                            wfr[nf], ifr, acc[m][nf], 0, 0, 0);   // row=cout, col=pos
                    else
                        acc[m][nf] = __builtin_amdgcn_mfma_f32_16x16x32_bf16(
                            ifr, wfr[nf], acc[m][nf], 0, 0, 0);   // row=pos, col=cout
                }
            }
        }
    }

    const float al = alpha[0];
    const int y = y0 + wv;
    if (OUT_NHWC) {
        float4 bv[4];
#pragma unroll
        for (int nf = 0; nf < 4; ++nf) bv[nf] = *(const float4*)(bias + nf * 16 + (l4 << 2));
#pragma unroll
        for (int m = 0; m < 2; ++m) {
            int x = x0 + m * 16 + l15;
#pragma unroll
            for (int nf = 0; nf < 4; ++nf) {
                f32x4 v = acc[m][nf];
                uint lo = pack2(prelu(v.x + bv[nf].x, al), prelu(v.y + bv[nf].y, al));
                uint hi = pack2(prelu(v.z + bv[nf].z, al), prelu(v.w + bv[nf].w, al));
                int cb = nf * 16 + (l4 << 2);
                *(uint2*)(outB + ((size_t)(b * HF + y) * WF + x) * 64 + cb) = make_uint2(lo, hi);
            }
        }
    } else {
        float bb[4];
#pragma unroll
        for (int nf = 0; nf < 4; ++nf) bb[nf] = bias[nf * 16 + l15];
#pragma unroll
        for (int m = 0; m < 2; ++m) {
            int xb = x0 + m * 16 + (l4 << 2);
#pragma unroll
            for (int nf = 0; nf < 4; ++nf) {
                f32x4 v = acc[m][nf];
                int cout = nf * 16 + l15;
                float4 st;
                st.x = prelu(v.x + bb[nf], al);
                st.y = prelu(v.y + bb[nf], al);
                st.z = prelu(v.z + bb[nf], al);
                st.w = prelu(v.w + bb[nf], al);
                *(float4*)(outF + (((size_t)b * 64 + cout) << 16) + y * WF + xb) = st;
            }
        }
    }
}

// ---------------------------------------------------------------------------
extern "C" void kernel_launch(void* const* d_in, const int* in_sizes, int n_in,
                              void* d_out, int out_size, void* d_ws, size_t ws_size,
                              hipStream_t stream) {
    const float* x1  = (const float*)d_in[0];
    const float* x2  = (const float*)d_in[1];
    const float* wup = (const float*)d_in[2];
    const float* bup = (const float*)d_in[3];
    const float* w1  = (const float*)d_in[4];
    const float* b1  = (const float*)d_in[5];
    const float* a1  = (const float*)d_in[6];
    const float* w2  = (const float*)d_in[7];
    const float* b2  = (const float*)d_in[8];
    const float* a2  = (const float*)d_in[9];

    char* ws = (char*)d_ws;
    ushort* upB  = (ushort*)ws;                          // 16 MiB (b=2,3 NHWC bf16)
    ushort* hB   = (ushort*)(ws + (size_t)(16 << 20));   // 32 MiB (NHWC bf16)
    ushort* wT1  = (ushort*)(ws + (size_t)(48 << 20));   // 72 KiB
    ushort* wT2  = wT1 + 9 * 64 * 64;                    // 72 KiB
    ushort* wupT = wT2 + 9 * 64 * 64;                    // 64 KiB
    uint4*  zeroBuf = (uint4*)(ws + (size_t)(49 << 20)); // 256 B, zeroed by k_wprep
    float* out = (float*)d_out;

    k_wprep<<<144, 256, 0, stream>>>(w1, w2, wup, wT1, wT2, wupT, zeroBuf);
    k_upsample_mfma<<<dim3(256, 2), 512, 0, stream>>>(x1, wupT, bup, upB);
    k_conv<0, 1><<<dim3(128, 4), 1024, 0, stream>>>(x2, upB, nullptr, wT1, b1, a1, zeroBuf, hB, nullptr);
    k_conv<1, 0><<<dim3(128, 4), 1024, 0, stream>>>(nullptr, nullptr, hB, wT2, b2, a2, zeroBuf, nullptr, out);
}